// Round 11
// baseline (3040.024 us; speedup 1.0000x reference)
//
#include <hip/hip_runtime.h>
#include <cstdint>
#include <cstddef>

typedef _Float16 f16x2 __attribute__((ext_vector_type(2)));
typedef _Float16 half4 __attribute__((ext_vector_type(4)));
typedef _Float16 half8 __attribute__((ext_vector_type(8)));
typedef float f32x4 __attribute__((ext_vector_type(4)));

static constexpr int BB = 64;    // batch
static constexpr int TT = 1024;  // time steps
static constexpr int FF = 512;   // input features
static constexpr int UU = 256;   // hidden units per direction
static constexpr int NZ = 1024;  // 4*UU gate width

// U on-CU split (per thread, 32 uint4 total): 20 reg + 8 LDS + 4 L2-stream
static constexpr int UREG = 20;
static constexpr int ULDS = 8;
static constexpr size_t ULDS_BYTES = (size_t)ULDS * 1024 * 16;   // 128 KiB
static constexpr size_t H_SECT = 144;                            // 128 data + 16 pad
static constexpr size_t LSTM_SHBYTES = ULDS_BYTES + 1024;        // ~129 KiB -> 1 block/CU

__device__ __forceinline__ f16x2 bc16(unsigned int v) { return __builtin_bit_cast(f16x2, v); }

// Raw barrier: drains LDS ops only; vmcnt (global loads) survives.
__device__ __forceinline__ void bar_lgkm()
{
    asm volatile("s_waitcnt lgkmcnt(0)\n\ts_barrier" ::: "memory");
}

// quad (4-lane) sum via DPP quad_perm: [1,0,3,2]=0xB1 then [2,3,0,1]=0x4E
__device__ __forceinline__ float qsum(float v)
{
    int b1 = __builtin_amdgcn_mov_dpp(__builtin_bit_cast(int, v), 0xB1, 0xf, 0xf, true);
    v += __builtin_bit_cast(float, b1);
    int b2 = __builtin_amdgcn_mov_dpp(__builtin_bit_cast(int, v), 0x4E, 0xf, 0xf, true);
    v += __builtin_bit_cast(float, b2);
    return v;
}

// ---------------------------------------------------------------------------
// Cast x fp32 -> f16 (flat)
// ---------------------------------------------------------------------------
__global__ __launch_bounds__(256) void enc_cast_x(
    const float* __restrict__ x, _Float16* __restrict__ x16, int n4)
{
    int stride = gridDim.x * 256;
    for (int i = blockIdx.x * 256 + threadIdx.x; i < n4; i += stride) {
        float4 v = ((const float4*)x)[i];
        half4 o;
        o.x = (_Float16)v.x; o.y = (_Float16)v.y;
        o.z = (_Float16)v.z; o.w = (_Float16)v.w;
        ((half4*)x16)[i] = o;
    }
}

// ---------------------------------------------------------------------------
// W [512,1024] fp32 -> WT [dir][1024][512] f16 (transposed)
// ---------------------------------------------------------------------------
__global__ __launch_bounds__(256) void enc_cast_wt(
    const float* __restrict__ Wf, const float* __restrict__ Wb,
    _Float16* __restrict__ WT)
{
    __shared__ float tile[64][65];
    const int t = threadIdx.x;
    const int k0 = blockIdx.x * 64;
    const int n0 = blockIdx.y * 64;
    const int d = blockIdx.z;
    const float* W = d ? Wb : Wf;
    _Float16* WTd = WT + (size_t)d * NZ * FF;
#pragma unroll
    for (int p = 0; p < 16; ++p) {
        int idx = p * 256 + t;
        int r = idx >> 6, c = idx & 63;
        tile[r][c] = W[(size_t)(k0 + r) * NZ + n0 + c];
    }
    __syncthreads();
#pragma unroll
    for (int p = 0; p < 16; ++p) {
        int idx = p * 256 + t;
        int r = idx >> 6, c = idx & 63;
        WTd[(size_t)(n0 + r) * FF + k0 + c] = (_Float16)tile[c][r];
    }
}

// ---------------------------------------------------------------------------
// Pack U: Upkr2[(d*128 + k2)*256 + j] = uint4 of 4 gate words;
// word g = { U_d[2*k2][g*256+j], U_d[2*k2+1][g*256+j] } as f16x2.
// ---------------------------------------------------------------------------
__global__ __launch_bounds__(256) void enc_pack_u16v2(
    const float* __restrict__ Uf, const float* __restrict__ Ub,
    uint4* __restrict__ Upkr2)
{
    int idx = blockIdx.x * 256 + threadIdx.x;     // 0 .. 65535
    if (idx >= 2 * 128 * 256) return;
    int d  = idx >> 15;
    int k2 = (idx >> 8) & 127;
    int j  = idx & 255;
    int k = 2 * k2;
    const float* Ud = d ? Ub : Uf;
    unsigned int w[4];
#pragma unroll
    for (int g = 0; g < 4; ++g) {
        f16x2 h;
        h.x = (_Float16)Ud[(size_t)k * NZ + g * 256 + j];
        h.y = (_Float16)Ud[(size_t)(k + 1) * NZ + g * 256 + j];
        w[g] = __builtin_bit_cast(unsigned int, h);
    }
    Upkr2[idx] = make_uint4(w[0], w[1], w[2], w[3]);
}

__global__ __launch_bounds__(256) void enc_zero(float* __restrict__ p, int n)
{
    int i = blockIdx.x * 256 + threadIdx.x;
    if (i < n) p[i] = 0.f;
}

// ---------------------------------------------------------------------------
// MFMA GEMM: xz16[r, n] = x16_row(r) . W_d[:, n] + b_d[n]   (unchanged)
// ---------------------------------------------------------------------------
__global__ __launch_bounds__(256) void enc_gemm16(
    const _Float16* __restrict__ x16, const _Float16* __restrict__ WT,
    const float* __restrict__ bf, const float* __restrict__ bb,
    _Float16* __restrict__ xz16, int c0, int CT)
{
    __shared__ __align__(16) _Float16 Ash[128][40];
    __shared__ __align__(16) _Float16 Bsh[128][40];

    const int t = threadIdx.x;
    const int r0 = blockIdx.x * 128;
    const int n0 = blockIdx.y * 128;
    const int MperD = BB * CT;
    const int d = r0 / MperD;

    const int srow = t >> 2;
    const int koff = (t & 3) * 8;

    auto xrowptr = [&](int r) -> const _Float16* {
        int rd = r - d * MperD;
        int b = rd / CT;
        int tl = rd - b * CT;
        int tsrc = d ? (TT - 1 - (c0 + tl)) : (c0 + tl);
        return x16 + ((size_t)b * TT + tsrc) * FF;
    };
    const _Float16* ap0 = xrowptr(r0 + srow);
    const _Float16* ap1 = xrowptr(r0 + 64 + srow);
    const _Float16* wp0 = WT + (size_t)(d * NZ + n0 + srow) * FF;
    const _Float16* wp1 = wp0 + (size_t)64 * FF;

    const int lane = t & 63;
    const int w = t >> 6;
    const int wm = w >> 1, wn = w & 1;
    const int l15 = lane & 15;
    const int kq = (lane >> 4) * 8;

    f32x4 acc[4][4];
#pragma unroll
    for (int i = 0; i < 4; ++i)
#pragma unroll
        for (int j = 0; j < 4; ++j) acc[i][j] = (f32x4)0.f;

    for (int ks = 0; ks < FF / 32; ++ks) {
        const int k0 = ks * 32;
        uint4 av0 = *(const uint4*)(ap0 + k0 + koff);
        uint4 av1 = *(const uint4*)(ap1 + k0 + koff);
        uint4 bv0 = *(const uint4*)(wp0 + k0 + koff);
        uint4 bv1 = *(const uint4*)(wp1 + k0 + koff);
        __syncthreads();
        *(uint4*)&Ash[srow][koff]      = av0;
        *(uint4*)&Ash[64 + srow][koff] = av1;
        *(uint4*)&Bsh[srow][koff]      = bv0;
        *(uint4*)&Bsh[64 + srow][koff] = bv1;
        __syncthreads();

        half8 af[4], bfr[4];
#pragma unroll
        for (int mf = 0; mf < 4; ++mf)
            af[mf] = *(const half8*)&Ash[wm * 64 + mf * 16 + l15][kq];
#pragma unroll
        for (int nf = 0; nf < 4; ++nf)
            bfr[nf] = *(const half8*)&Bsh[wn * 64 + nf * 16 + l15][kq];
#pragma unroll
        for (int mf = 0; mf < 4; ++mf)
#pragma unroll
            for (int nf = 0; nf < 4; ++nf)
                acc[mf][nf] = __builtin_amdgcn_mfma_f32_16x16x32_f16(
                    af[mf], bfr[nf], acc[mf][nf], 0, 0, 0);
    }

    const float* bd = d ? bb : bf;
    const int rbase = r0 + wm * 64;
    const int cbase = n0 + wn * 64;
#pragma unroll
    for (int nf = 0; nf < 4; ++nf) {
        const int cc = cbase + nf * 16 + l15;
        const float bia = bd[cc];
#pragma unroll
        for (int mf = 0; mf < 4; ++mf) {
#pragma unroll
            for (int rg = 0; rg < 4; ++rg) {
                int rr = rbase + mf * 16 + (lane >> 4) * 4 + rg;
                xz16[(size_t)rr * NZ + cc] = (_Float16)(acc[mf][nf][rg] + bia);
            }
        }
    }
}

// ---------------------------------------------------------------------------
// Single-CU full-chain recurrence: 128 blocks = chains, 1024 threads.
// __launch_bounds__(1024, 4): 16 waves = 4 waves/EU declared -> VGPR cap 128
// (R10 failed here: default heuristic capped at 64 and rematerialized the
// "register" U tier as per-step L2 loads -> 2.1us/step).
// t = j*4 + q: lane q owns k-quarter q x 4 gates of unit j.
// U 3-tier: ureg[20] + ulds[8][1024] + 4 uint4 L2-streamed (anti-hoisted).
// h[256] f16 in LDS: 4 sections of 144 B -> quad broadcast reads hit
// distinct banks. Quad-DPP reduce -> every lane has full z; gates dup x4.
// 2 raw lgkm barriers/step; no cross-CU exchange, no spin.
// ---------------------------------------------------------------------------
__device__ __forceinline__ float sigm_f(float xv)
{
    return 1.0f / (1.0f + __expf(-xv));
}
__device__ __forceinline__ float tanh_f(float xv)
{
    return 2.0f / (1.0f + __expf(-2.0f * xv)) - 1.0f;
}

__global__ __launch_bounds__(1024, 4) void enc_lstm_full(
    const _Float16* __restrict__ xz16, const uint4* __restrict__ Upkr2,
    float* __restrict__ hstate, float* __restrict__ cstate,
    float* __restrict__ out, int c0, int CT)
{
    extern __shared__ char smem2[];
    uint4* ulds = (uint4*)smem2;                     // [8][1024] uint4
    char*  hbase = smem2 + ULDS_BYTES;               // 4 sections x 144 B

    const int t = threadIdx.x;
    const int q = t & 3;
    const int j = t >> 2;          // 0..255
    const int c = blockIdx.x;      // chain 0..127
    const int d = c >> 6;
    const int b = c & 63;
    const int jq4 = t;             // = j*4 + q, LDS-U index

    // ---- persistent U ----
    const uint4* Uq = Upkr2 + ((size_t)d * 128 + q * 32) * 256 + j;
    uint4 ureg[UREG];
#pragma unroll
    for (int m = 0; m < UREG; ++m) ureg[m] = Uq[(size_t)m * 256];
#pragma unroll
    for (int m = 0; m < ULDS; ++m)
        ulds[(size_t)m * 1024 + jq4] = Uq[(size_t)(UREG + m) * 256];

    // ---- state init ----
    float cr = cstate[(size_t)c * UU + j];           // duplicated across quad
    float hn = 0.f;
    if (t < 256) {
        _Float16 hv = (_Float16)hstate[(size_t)c * UU + t];
        *(unsigned short*)(hbase + (t >> 6) * H_SECT + (t & 63) * 2) =
            __builtin_bit_cast(unsigned short, hv);
    }
    __syncthreads();

    const _Float16* xzrow = xz16 + (size_t)c * CT * NZ;
    float* outb = out + (size_t)b * TT * (2 * UU) + d * UU;
    const char* hrd = hbase + q * H_SECT;            // this lane's h quarter

    // first step's xz (gate q of unit j)
    unsigned short xq = *((const unsigned short*)xzrow + q * 256 + j);

    for (int tl = 0; tl < CT; ++tl) {
        // L2-tier U loads. Anti-hoist: obscure the offset so these stay
        // in-loop L2 hits (hoisting them would cost 16 VGPRs -> spill risk).
        int zoff = 0;
        asm volatile("" : "+v"(zoff));
        const uint4* Ul2 = Uq + (size_t)(UREG + ULDS) * 256 + zoff;
        uint4 u28 = Ul2[0];
        uint4 u29 = Ul2[256];
        uint4 u30 = Ul2[512];
        uint4 u31 = Ul2[768];

        float a0 = 0.f, a1 = 0.f, a2 = 0.f, a3 = 0.f;
        auto dotw = [&](const uint4& uv, unsigned int hw) {
            f16x2 h2 = bc16(hw);
            a0 = __builtin_amdgcn_fdot2(h2, bc16(uv.x), a0, false);
            a1 = __builtin_amdgcn_fdot2(h2, bc16(uv.y), a1, false);
            a2 = __builtin_amdgcn_fdot2(h2, bc16(uv.z), a2, false);
            a3 = __builtin_amdgcn_fdot2(h2, bc16(uv.w), a3, false);
        };

        // reg tier: h uint4 r covers k2 4r..4r+3 -> U words 4r..4r+3
#pragma unroll
        for (int r = 0; r < 5; ++r) {
            uint4 hq = *(const uint4*)(hrd + r * 16);
            dotw(ureg[4 * r + 0], hq.x);
            dotw(ureg[4 * r + 1], hq.y);
            dotw(ureg[4 * r + 2], hq.z);
            dotw(ureg[4 * r + 3], hq.w);
        }
        // LDS tier: U words 20..27 (read just-in-time, low pressure)
#pragma unroll
        for (int r = 5; r < 7; ++r) {
            uint4 hq = *(const uint4*)(hrd + r * 16);
#pragma unroll
            for (int e = 0; e < 4; ++e) {
                uint4 uv = ulds[(size_t)(4 * (r - 5) + e) * 1024 + jq4];
                dotw(uv, (&hq.x)[e]);
            }
        }
        // L2 tier: U words 28..31
        {
            uint4 hq = *(const uint4*)(hrd + 7 * 16);
            dotw(u28, hq.x);
            dotw(u29, hq.y);
            dotw(u30, hq.z);
            dotw(u31, hq.w);
        }

        // inject xz on lane q into accumulator q (summed once by quad reduce)
        {
            float xv = (float)__builtin_bit_cast(_Float16, xq);
            a0 += (q == 0) ? xv : 0.f;
            a1 += (q == 1) ? xv : 0.f;
            a2 += (q == 2) ? xv : 0.f;
            a3 += (q == 3) ? xv : 0.f;
        }
        float zi = qsum(a0), zf = qsum(a1), zg = qsum(a2), zo = qsum(a3);

        // gates (duplicated across quad — deterministic identical results)
        float ig = sigm_f(zi), fg = sigm_f(zf), gg = tanh_f(zg), og = sigm_f(zo);
        cr = fg * cr + ig * gg;
        hn = og * tanh_f(cr);
        unsigned short hbits =
            __builtin_bit_cast(unsigned short, (_Float16)hn);

        // prefetch next step's xz (vmcnt survives raw barriers)
        {
            int tn = (tl + 1 < CT) ? tl + 1 : tl;
            xq = *((const unsigned short*)(xzrow + (size_t)tn * NZ) + q * 256 + j);
        }

        bar_lgkm();                          // bar1: all h reads complete
        if (q == 0) {
            *(unsigned short*)(hbase + (j >> 6) * H_SECT + (j & 63) * 2) = hbits;
            int tsrc = d ? (TT - 1 - (c0 + tl)) : (c0 + tl);
            outb[(size_t)tsrc * (2 * UU) + j] = hn;
        }
        bar_lgkm();                          // bar2: new h visible
    }

    if (q == 0) {
        hstate[(size_t)c * UU + j] = hn;
        cstate[(size_t)c * UU + j] = cr;
    }
}

// ---------------------------------------------------------------------------
// Final h/c copy into d_out tail sections
// ---------------------------------------------------------------------------
__global__ __launch_bounds__(256) void enc_final(
    const float* __restrict__ hstate, const float* __restrict__ cstate,
    float* __restrict__ out)
{
    int idx = blockIdx.x * 256 + threadIdx.x;
    if (idx >= 2 * BB * UU) return;
    int d = idx / (BB * UU);
    int rem = idx - d * (BB * UU);
    int b = rem / UU;
    int j = rem - b * UU;
    size_t OUT_H = (size_t)BB * TT * (2 * UU);
    size_t HSZ = (size_t)BB * (2 * UU);
    out[OUT_H + (size_t)b * (2 * UU) + d * UU + j] = hstate[idx];
    out[OUT_H + HSZ + (size_t)b * (2 * UU) + d * UU + j] = cstate[idx];
}

// ---------------------------------------------------------------------------
extern "C" void kernel_launch(void* const* d_in, const int* in_sizes, int n_in,
                              void* d_out, int out_size, void* d_ws, size_t ws_size,
                              hipStream_t stream)
{
    const float* x  = (const float*)d_in[0];
    const float* Wf = (const float*)d_in[1];
    const float* Uf = (const float*)d_in[2];
    const float* bf = (const float*)d_in[3];
    const float* Wb = (const float*)d_in[4];
    const float* Ub = (const float*)d_in[5];
    const float* bb = (const float*)d_in[6];
    float* out = (float*)d_out;

    const size_t x16_bytes   = (size_t)BB * TT * FF * 2;             // 64 MiB
    const size_t wt_bytes    = (size_t)2 * NZ * FF * 2;              // 2 MiB
    const size_t upk_bytes   = (size_t)2 * 128 * 256 * sizeof(uint4);// 1 MiB
    const size_t state_bytes = (size_t)2 * BB * UU * sizeof(float);  // 128 KiB each
    const size_t fixed = x16_bytes + wt_bytes + upk_bytes + 2 * state_bytes;

    int CT = TT;
    while (CT > 8) {
        size_t need = fixed + (size_t)2 * BB * CT * NZ * 2;
        if (need <= ws_size) break;
        CT >>= 1;
    }

    char* wsb = (char*)d_ws;
    _Float16* x16 = (_Float16*)wsb;
    _Float16* WT  = (_Float16*)(wsb + x16_bytes);
    uint4* Upkr2  = (uint4*)(wsb + x16_bytes + wt_bytes);
    float* hstate = (float*)(wsb + x16_bytes + wt_bytes + upk_bytes);
    float* cstate = hstate + 2 * BB * UU;
    _Float16* xz16 = (_Float16*)(wsb + fixed);

    (void)hipFuncSetAttribute(reinterpret_cast<const void*>(enc_lstm_full),
                              hipFuncAttributeMaxDynamicSharedMemorySize,
                              (int)LSTM_SHBYTES);

    enc_cast_x<<<4096, 256, 0, stream>>>(x, x16, BB * TT * FF / 4);
    enc_cast_wt<<<dim3(8, 16, 2), 256, 0, stream>>>(Wf, Wb, WT);
    enc_pack_u16v2<<<(2 * 128 * 256 + 255) / 256, 256, 0, stream>>>(Uf, Ub, Upkr2);
    enc_zero<<<(2 * 2 * BB * UU + 255) / 256, 256, 0, stream>>>(hstate, 2 * 2 * BB * UU);

    for (int c0 = 0; c0 < TT; c0 += CT) {
        dim3 ggrid((2 * BB * CT) / 128, NZ / 128);
        enc_gemm16<<<ggrid, 256, 0, stream>>>(x16, WT, bf, bb, xz16, c0, CT);
        enc_lstm_full<<<128, 1024, LSTM_SHBYTES, stream>>>(
            xz16, Upkr2, hstate, cstate, out, c0, CT);
    }
    enc_final<<<(2 * BB * UU + 255) / 256, 256, 0, stream>>>(hstate, cstate, out);
}

// Round 12
// 2311.374 us; speedup vs baseline: 1.3152x; 1.3152x over previous
//
#include <hip/hip_runtime.h>
#include <cstdint>
#include <cstddef>

typedef _Float16 f16x2 __attribute__((ext_vector_type(2)));
typedef _Float16 half4 __attribute__((ext_vector_type(4)));
typedef _Float16 half8 __attribute__((ext_vector_type(8)));
typedef float f32x4 __attribute__((ext_vector_type(4)));
typedef unsigned int u32x4 __attribute__((ext_vector_type(4)));

static constexpr int BB = 64;    // batch
static constexpr int TT = 1024;  // time steps
static constexpr int FF = 512;   // input features
static constexpr int UU = 256;   // hidden units per direction
static constexpr int NZ = 1024;  // 4*UU gate width

// U on-CU split (per thread, 32 uint4 total): 22 asm-pinned reg + 9 LDS + 1 free
static constexpr int UREG = 22;
static constexpr int ULDS = 9;
static constexpr size_t ULDS_BYTES = (size_t)ULDS * 1024 * 16;   // 144 KiB
static constexpr size_t H_SECT = 144;                            // 128 data + 16 pad
static constexpr size_t LSTM_SHBYTES = ULDS_BYTES + 1024;        // ~145 KiB -> 1 block/CU

__device__ __forceinline__ f16x2 bc16(unsigned int v) { return __builtin_bit_cast(f16x2, v); }

// Raw barrier: drains LDS ops only; vmcnt (global loads) survives.
__device__ __forceinline__ void bar_lgkm()
{
    asm volatile("s_waitcnt lgkmcnt(0)\n\ts_barrier" ::: "memory");
}

// quad (4-lane) sum via DPP quad_perm: [1,0,3,2]=0xB1 then [2,3,0,1]=0x4E
__device__ __forceinline__ float qsum(float v)
{
    int b1 = __builtin_amdgcn_mov_dpp(__builtin_bit_cast(int, v), 0xB1, 0xf, 0xf, true);
    v += __builtin_bit_cast(float, b1);
    int b2 = __builtin_amdgcn_mov_dpp(__builtin_bit_cast(int, v), 0x4E, 0xf, 0xf, true);
    v += __builtin_bit_cast(float, b2);
    return v;
}

// ---------------------------------------------------------------------------
// Cast x fp32 -> f16 (flat)
// ---------------------------------------------------------------------------
__global__ __launch_bounds__(256) void enc_cast_x(
    const float* __restrict__ x, _Float16* __restrict__ x16, int n4)
{
    int stride = gridDim.x * 256;
    for (int i = blockIdx.x * 256 + threadIdx.x; i < n4; i += stride) {
        float4 v = ((const float4*)x)[i];
        half4 o;
        o.x = (_Float16)v.x; o.y = (_Float16)v.y;
        o.z = (_Float16)v.z; o.w = (_Float16)v.w;
        ((half4*)x16)[i] = o;
    }
}

// ---------------------------------------------------------------------------
// W [512,1024] fp32 -> WT [dir][1024][512] f16 (transposed)
// ---------------------------------------------------------------------------
__global__ __launch_bounds__(256) void enc_cast_wt(
    const float* __restrict__ Wf, const float* __restrict__ Wb,
    _Float16* __restrict__ WT)
{
    __shared__ float tile[64][65];
    const int t = threadIdx.x;
    const int k0 = blockIdx.x * 64;
    const int n0 = blockIdx.y * 64;
    const int d = blockIdx.z;
    const float* W = d ? Wb : Wf;
    _Float16* WTd = WT + (size_t)d * NZ * FF;
#pragma unroll
    for (int p = 0; p < 16; ++p) {
        int idx = p * 256 + t;
        int r = idx >> 6, c = idx & 63;
        tile[r][c] = W[(size_t)(k0 + r) * NZ + n0 + c];
    }
    __syncthreads();
#pragma unroll
    for (int p = 0; p < 16; ++p) {
        int idx = p * 256 + t;
        int r = idx >> 6, c = idx & 63;
        WTd[(size_t)(n0 + r) * FF + k0 + c] = (_Float16)tile[c][r];
    }
}

// ---------------------------------------------------------------------------
// Pack U: Upkr2[(d*128 + k2)*256 + j] = uint4 of 4 gate words;
// word g = { U_d[2*k2][g*256+j], U_d[2*k2+1][g*256+j] } as f16x2.
// ---------------------------------------------------------------------------
__global__ __launch_bounds__(256) void enc_pack_u16v2(
    const float* __restrict__ Uf, const float* __restrict__ Ub,
    uint4* __restrict__ Upkr2)
{
    int idx = blockIdx.x * 256 + threadIdx.x;     // 0 .. 65535
    if (idx >= 2 * 128 * 256) return;
    int d  = idx >> 15;
    int k2 = (idx >> 8) & 127;
    int j  = idx & 255;
    int k = 2 * k2;
    const float* Ud = d ? Ub : Uf;
    unsigned int w[4];
#pragma unroll
    for (int g = 0; g < 4; ++g) {
        f16x2 h;
        h.x = (_Float16)Ud[(size_t)k * NZ + g * 256 + j];
        h.y = (_Float16)Ud[(size_t)(k + 1) * NZ + g * 256 + j];
        w[g] = __builtin_bit_cast(unsigned int, h);
    }
    Upkr2[idx] = make_uint4(w[0], w[1], w[2], w[3]);
}

__global__ __launch_bounds__(256) void enc_zero(float* __restrict__ p, int n)
{
    int i = blockIdx.x * 256 + threadIdx.x;
    if (i < n) p[i] = 0.f;
}

// ---------------------------------------------------------------------------
// MFMA GEMM: xz16[r, n] = x16_row(r) . W_d[:, n] + b_d[n]   (unchanged)
// ---------------------------------------------------------------------------
__global__ __launch_bounds__(256) void enc_gemm16(
    const _Float16* __restrict__ x16, const _Float16* __restrict__ WT,
    const float* __restrict__ bf, const float* __restrict__ bb,
    _Float16* __restrict__ xz16, int c0, int CT)
{
    __shared__ __align__(16) _Float16 Ash[128][40];
    __shared__ __align__(16) _Float16 Bsh[128][40];

    const int t = threadIdx.x;
    const int r0 = blockIdx.x * 128;
    const int n0 = blockIdx.y * 128;
    const int MperD = BB * CT;
    const int d = r0 / MperD;

    const int srow = t >> 2;
    const int koff = (t & 3) * 8;

    auto xrowptr = [&](int r) -> const _Float16* {
        int rd = r - d * MperD;
        int b = rd / CT;
        int tl = rd - b * CT;
        int tsrc = d ? (TT - 1 - (c0 + tl)) : (c0 + tl);
        return x16 + ((size_t)b * TT + tsrc) * FF;
    };
    const _Float16* ap0 = xrowptr(r0 + srow);
    const _Float16* ap1 = xrowptr(r0 + 64 + srow);
    const _Float16* wp0 = WT + (size_t)(d * NZ + n0 + srow) * FF;
    const _Float16* wp1 = wp0 + (size_t)64 * FF;

    const int lane = t & 63;
    const int w = t >> 6;
    const int wm = w >> 1, wn = w & 1;
    const int l15 = lane & 15;
    const int kq = (lane >> 4) * 8;

    f32x4 acc[4][4];
#pragma unroll
    for (int i = 0; i < 4; ++i)
#pragma unroll
        for (int j = 0; j < 4; ++j) acc[i][j] = (f32x4)0.f;

    for (int ks = 0; ks < FF / 32; ++ks) {
        const int k0 = ks * 32;
        uint4 av0 = *(const uint4*)(ap0 + k0 + koff);
        uint4 av1 = *(const uint4*)(ap1 + k0 + koff);
        uint4 bv0 = *(const uint4*)(wp0 + k0 + koff);
        uint4 bv1 = *(const uint4*)(wp1 + k0 + koff);
        __syncthreads();
        *(uint4*)&Ash[srow][koff]      = av0;
        *(uint4*)&Ash[64 + srow][koff] = av1;
        *(uint4*)&Bsh[srow][koff]      = bv0;
        *(uint4*)&Bsh[64 + srow][koff] = bv1;
        __syncthreads();

        half8 af[4], bfr[4];
#pragma unroll
        for (int mf = 0; mf < 4; ++mf)
            af[mf] = *(const half8*)&Ash[wm * 64 + mf * 16 + l15][kq];
#pragma unroll
        for (int nf = 0; nf < 4; ++nf)
            bfr[nf] = *(const half8*)&Bsh[wn * 64 + nf * 16 + l15][kq];
#pragma unroll
        for (int mf = 0; mf < 4; ++mf)
#pragma unroll
            for (int nf = 0; nf < 4; ++nf)
                acc[mf][nf] = __builtin_amdgcn_mfma_f32_16x16x32_f16(
                    af[mf], bfr[nf], acc[mf][nf], 0, 0, 0);
    }

    const float* bd = d ? bb : bf;
    const int rbase = r0 + wm * 64;
    const int cbase = n0 + wn * 64;
#pragma unroll
    for (int nf = 0; nf < 4; ++nf) {
        const int cc = cbase + nf * 16 + l15;
        const float bia = bd[cc];
#pragma unroll
        for (int mf = 0; mf < 4; ++mf) {
#pragma unroll
            for (int rg = 0; rg < 4; ++rg) {
                int rr = rbase + mf * 16 + (lane >> 4) * 4 + rg;
                xz16[(size_t)rr * NZ + cc] = (_Float16)(acc[mf][nf][rg] + bia);
            }
        }
    }
}

// ---------------------------------------------------------------------------
// Single-CU full-chain recurrence, asm-pinned U register tier.
// 128 blocks = chains, 1024 threads. t = j*4 + q: lane q owns k-quarter q
// x 4 gates of unit j (32 uint4 of U). Tiers: 22 words ASM-PINNED in VGPRs
// (the compiler rematerialized plain loads in R10/R11 -> L2 stream; an asm
// output cannot be rematerialized), 9 words LDS [9][1024], 1 word left to
// the compiler (hoist or L2 re-load, its call).
// h[256] f16 in LDS: 4 sections of 144 B -> quad broadcast reads hit
// distinct banks. Quad-DPP reduce -> every lane has full z; gates dup x4.
// 2 raw lgkm barriers/step; no cross-CU exchange, no spin.
// ---------------------------------------------------------------------------
__device__ __forceinline__ float sigm_f(float xv)
{
    return 1.0f / (1.0f + __expf(-xv));
}
__device__ __forceinline__ float tanh_f(float xv)
{
    return 2.0f / (1.0f + __expf(-2.0f * xv)) - 1.0f;
}

__global__ __launch_bounds__(1024, 4) void enc_lstm_full(
    const _Float16* __restrict__ xz16, const uint4* __restrict__ Upkr2,
    float* __restrict__ hstate, float* __restrict__ cstate,
    float* __restrict__ out, int c0, int CT)
{
    extern __shared__ char smem2[];
    u32x4* ulds = (u32x4*)smem2;                     // [9][1024] u32x4
    char*  hbase = smem2 + ULDS_BYTES;               // 4 sections x 144 B

    const int t = threadIdx.x;
    const int q = t & 3;
    const int j = t >> 2;          // 0..255
    const int c = blockIdx.x;      // chain 0..127
    const int d = c >> 6;
    const int b = c & 63;
    const int jq4 = t;             // = j*4 + q, LDS-U index

    // ---- persistent U ----
    const u32x4* Uq = (const u32x4*)(Upkr2 + ((size_t)d * 128 + q * 32) * 256 + j);

    // register tier: ASM loads -> outputs cannot be rematerialized
    u32x4 ureg[UREG];
#pragma unroll
    for (int m = 0; m < UREG; ++m) {
        const u32x4* p = Uq + (size_t)m * 256;
        asm volatile("global_load_dwordx4 %0, %1, off"
                     : "=v"(ureg[m]) : "v"(p) : "memory");
    }
    // LDS tier: words 22..30
#pragma unroll
    for (int m = 0; m < ULDS; ++m)
        ulds[(size_t)m * 1024 + jq4] = Uq[(size_t)(UREG + m) * 256];
    // free-tier address (word 31): compiler may hoist the load or re-load L2
    const u32x4* Ufree = Uq + (size_t)31 * 256;

    asm volatile("s_waitcnt vmcnt(0)" ::: "memory");
    __builtin_amdgcn_sched_barrier(0);               // rule #18 fence

    // ---- state init ----
    float cr = cstate[(size_t)c * UU + j];           // duplicated across quad
    float hn = 0.f;
    if (t < 256) {
        _Float16 hv = (_Float16)hstate[(size_t)c * UU + t];
        *(unsigned short*)(hbase + (t >> 6) * H_SECT + (t & 63) * 2) =
            __builtin_bit_cast(unsigned short, hv);
    }
    __syncthreads();

    const _Float16* xzrow = xz16 + (size_t)c * CT * NZ;
    float* outb = out + (size_t)b * TT * (2 * UU) + d * UU;
    const char* hrd = hbase + q * H_SECT;            // this lane's h quarter

    // first step's xz (gate q of unit j)
    unsigned short xq = *((const unsigned short*)xzrow + q * 256 + j);

    for (int tl = 0; tl < CT; ++tl) {
        u32x4 u31 = *Ufree;

        float a0 = 0.f, a1 = 0.f, a2 = 0.f, a3 = 0.f;
        auto dotw = [&](const u32x4& uv, unsigned int hw) {
            f16x2 h2 = bc16(hw);
            a0 = __builtin_amdgcn_fdot2(h2, bc16(uv.x), a0, false);
            a1 = __builtin_amdgcn_fdot2(h2, bc16(uv.y), a1, false);
            a2 = __builtin_amdgcn_fdot2(h2, bc16(uv.z), a2, false);
            a3 = __builtin_amdgcn_fdot2(h2, bc16(uv.w), a3, false);
        };

        // r = 0..4: pure register tier (words 0..19)
#pragma unroll
        for (int r = 0; r < 5; ++r) {
            u32x4 hq = *(const u32x4*)(hrd + r * 16);
            dotw(ureg[4 * r + 0], hq.x);
            dotw(ureg[4 * r + 1], hq.y);
            dotw(ureg[4 * r + 2], hq.z);
            dotw(ureg[4 * r + 3], hq.w);
        }
        // r = 5: words 20,21 reg; 22,23 LDS rows 0,1
        {
            u32x4 hq = *(const u32x4*)(hrd + 5 * 16);
            dotw(ureg[20], hq.x);
            dotw(ureg[21], hq.y);
            dotw(ulds[(size_t)0 * 1024 + jq4], hq.z);
            dotw(ulds[(size_t)1 * 1024 + jq4], hq.w);
        }
        // r = 6: words 24..27 = LDS rows 2..5
        {
            u32x4 hq = *(const u32x4*)(hrd + 6 * 16);
            dotw(ulds[(size_t)2 * 1024 + jq4], hq.x);
            dotw(ulds[(size_t)3 * 1024 + jq4], hq.y);
            dotw(ulds[(size_t)4 * 1024 + jq4], hq.z);
            dotw(ulds[(size_t)5 * 1024 + jq4], hq.w);
        }
        // r = 7: words 28..30 = LDS rows 6..8; word 31 = free tier
        {
            u32x4 hq = *(const u32x4*)(hrd + 7 * 16);
            dotw(ulds[(size_t)6 * 1024 + jq4], hq.x);
            dotw(ulds[(size_t)7 * 1024 + jq4], hq.y);
            dotw(ulds[(size_t)8 * 1024 + jq4], hq.z);
            dotw(u31, hq.w);
        }

        // inject xz on lane q into accumulator q (summed once by quad reduce)
        {
            float xv = (float)__builtin_bit_cast(_Float16, xq);
            a0 += (q == 0) ? xv : 0.f;
            a1 += (q == 1) ? xv : 0.f;
            a2 += (q == 2) ? xv : 0.f;
            a3 += (q == 3) ? xv : 0.f;
        }
        float zi = qsum(a0), zf = qsum(a1), zg = qsum(a2), zo = qsum(a3);

        // gates (duplicated across quad — deterministic identical results)
        float ig = sigm_f(zi), fg = sigm_f(zf), gg = tanh_f(zg), og = sigm_f(zo);
        cr = fg * cr + ig * gg;
        hn = og * tanh_f(cr);
        unsigned short hbits =
            __builtin_bit_cast(unsigned short, (_Float16)hn);

        // prefetch next step's xz (vmcnt survives raw barriers)
        {
            int tn = (tl + 1 < CT) ? tl + 1 : tl;
            xq = *((const unsigned short*)(xzrow + (size_t)tn * NZ) + q * 256 + j);
        }

        bar_lgkm();                          // bar1: all h reads complete
        if (q == 0) {
            *(unsigned short*)(hbase + (j >> 6) * H_SECT + (j & 63) * 2) = hbits;
            int tsrc = d ? (TT - 1 - (c0 + tl)) : (c0 + tl);
            outb[(size_t)tsrc * (2 * UU) + j] = hn;
        }
        bar_lgkm();                          // bar2: new h visible
    }

    if (q == 0) {
        hstate[(size_t)c * UU + j] = hn;
        cstate[(size_t)c * UU + j] = cr;
    }
}

// ---------------------------------------------------------------------------
// Final h/c copy into d_out tail sections
// ---------------------------------------------------------------------------
__global__ __launch_bounds__(256) void enc_final(
    const float* __restrict__ hstate, const float* __restrict__ cstate,
    float* __restrict__ out)
{
    int idx = blockIdx.x * 256 + threadIdx.x;
    if (idx >= 2 * BB * UU) return;
    int d = idx / (BB * UU);
    int rem = idx - d * (BB * UU);
    int b = rem / UU;
    int j = rem - b * UU;
    size_t OUT_H = (size_t)BB * TT * (2 * UU);
    size_t HSZ = (size_t)BB * (2 * UU);
    out[OUT_H + (size_t)b * (2 * UU) + d * UU + j] = hstate[idx];
    out[OUT_H + HSZ + (size_t)b * (2 * UU) + d * UU + j] = cstate[idx];
}

// ---------------------------------------------------------------------------
extern "C" void kernel_launch(void* const* d_in, const int* in_sizes, int n_in,
                              void* d_out, int out_size, void* d_ws, size_t ws_size,
                              hipStream_t stream)
{
    const float* x  = (const float*)d_in[0];
    const float* Wf = (const float*)d_in[1];
    const float* Uf = (const float*)d_in[2];
    const float* bf = (const float*)d_in[3];
    const float* Wb = (const float*)d_in[4];
    const float* Ub = (const float*)d_in[5];
    const float* bb = (const float*)d_in[6];
    float* out = (float*)d_out;

    const size_t x16_bytes   = (size_t)BB * TT * FF * 2;             // 64 MiB
    const size_t wt_bytes    = (size_t)2 * NZ * FF * 2;              // 2 MiB
    const size_t upk_bytes   = (size_t)2 * 128 * 256 * sizeof(uint4);// 1 MiB
    const size_t state_bytes = (size_t)2 * BB * UU * sizeof(float);  // 128 KiB each
    const size_t fixed = x16_bytes + wt_bytes + upk_bytes + 2 * state_bytes;

    int CT = TT;
    while (CT > 8) {
        size_t need = fixed + (size_t)2 * BB * CT * NZ * 2;
        if (need <= ws_size) break;
        CT >>= 1;
    }

    char* wsb = (char*)d_ws;
    _Float16* x16 = (_Float16*)wsb;
    _Float16* WT  = (_Float16*)(wsb + x16_bytes);
    uint4* Upkr2  = (uint4*)(wsb + x16_bytes + wt_bytes);
    float* hstate = (float*)(wsb + x16_bytes + wt_bytes + upk_bytes);
    float* cstate = hstate + 2 * BB * UU;
    _Float16* xz16 = (_Float16*)(wsb + fixed);

    (void)hipFuncSetAttribute(reinterpret_cast<const void*>(enc_lstm_full),
                              hipFuncAttributeMaxDynamicSharedMemorySize,
                              (int)LSTM_SHBYTES);

    enc_cast_x<<<4096, 256, 0, stream>>>(x, x16, BB * TT * FF / 4);
    enc_cast_wt<<<dim3(8, 16, 2), 256, 0, stream>>>(Wf, Wb, WT);
    enc_pack_u16v2<<<(2 * 128 * 256 + 255) / 256, 256, 0, stream>>>(Uf, Ub, Upkr2);
    enc_zero<<<(2 * 2 * BB * UU + 255) / 256, 256, 0, stream>>>(hstate, 2 * 2 * BB * UU);

    for (int c0 = 0; c0 < TT; c0 += CT) {
        dim3 ggrid((2 * BB * CT) / 128, NZ / 128);
        enc_gemm16<<<ggrid, 256, 0, stream>>>(x16, WT, bf, bb, xz16, c0, CT);
        enc_lstm_full<<<128, 1024, LSTM_SHBYTES, stream>>>(
            xz16, Upkr2, hstate, cstate, out, c0, CT);
    }
    enc_final<<<(2 * BB * UU + 255) / 256, 256, 0, stream>>>(hstate, cstate, out);
}

// Round 14
// 1940.528 us; speedup vs baseline: 1.5666x; 1.1911x over previous
//
#include <hip/hip_runtime.h>
#include <cstdint>
#include <cstddef>

typedef _Float16 f16x2 __attribute__((ext_vector_type(2)));
typedef _Float16 half4 __attribute__((ext_vector_type(4)));
typedef _Float16 half8 __attribute__((ext_vector_type(8)));
typedef float f32x4 __attribute__((ext_vector_type(4)));
typedef unsigned int u32x4 __attribute__((ext_vector_type(4)));

static constexpr int BB = 64;    // batch
static constexpr int TT = 1024;  // time steps
static constexpr int FF = 512;   // input features
static constexpr int UU = 256;   // hidden units per direction
static constexpr int NZ = 1024;  // 4*UU gate width

// Pair-split recurrence: per thread 64 uint4 of U = 48 asm-pinned VGPR + 16 LDS
static constexpr int UREG = 48;
static constexpr int ULDS = 16;
static constexpr size_t ULDS_BYTES = (size_t)ULDS * 512 * 16;    // 128 KiB
static constexpr size_t LSTM_SHBYTES = ULDS_BYTES + 1024;        // ~129 KiB -> 1 block/CU

__device__ __forceinline__ f16x2 bc16(unsigned int v) { return __builtin_bit_cast(f16x2, v); }

// Raw barrier: drains LDS ops only; vmcnt (global loads) survives.
__device__ __forceinline__ void bar_lgkm()
{
    asm volatile("s_waitcnt lgkmcnt(0)\n\ts_barrier" ::: "memory");
}

// pair (2-lane) sum via DPP quad_perm [1,0,3,2] = 0xB1 (swaps lane pairs)
__device__ __forceinline__ float psum(float v)
{
    int b1 = __builtin_amdgcn_mov_dpp(__builtin_bit_cast(int, v), 0xB1, 0xf, 0xf, true);
    return v + __builtin_bit_cast(float, b1);
}

// ---------------------------------------------------------------------------
// Cast x fp32 -> f16 (flat)
// ---------------------------------------------------------------------------
__global__ __launch_bounds__(256) void enc_cast_x(
    const float* __restrict__ x, _Float16* __restrict__ x16, int n4)
{
    int stride = gridDim.x * 256;
    for (int i = blockIdx.x * 256 + threadIdx.x; i < n4; i += stride) {
        float4 v = ((const float4*)x)[i];
        half4 o;
        o.x = (_Float16)v.x; o.y = (_Float16)v.y;
        o.z = (_Float16)v.z; o.w = (_Float16)v.w;
        ((half4*)x16)[i] = o;
    }
}

// ---------------------------------------------------------------------------
// W [512,1024] fp32 -> WT [dir][1024][512] f16 (transposed)
// ---------------------------------------------------------------------------
__global__ __launch_bounds__(256) void enc_cast_wt(
    const float* __restrict__ Wf, const float* __restrict__ Wb,
    _Float16* __restrict__ WT)
{
    __shared__ float tile[64][65];
    const int t = threadIdx.x;
    const int k0 = blockIdx.x * 64;
    const int n0 = blockIdx.y * 64;
    const int d = blockIdx.z;
    const float* W = d ? Wb : Wf;
    _Float16* WTd = WT + (size_t)d * NZ * FF;
#pragma unroll
    for (int p = 0; p < 16; ++p) {
        int idx = p * 256 + t;
        int r = idx >> 6, c = idx & 63;
        tile[r][c] = W[(size_t)(k0 + r) * NZ + n0 + c];
    }
    __syncthreads();
#pragma unroll
    for (int p = 0; p < 16; ++p) {
        int idx = p * 256 + t;
        int r = idx >> 6, c = idx & 63;
        WTd[(size_t)(n0 + r) * FF + k0 + c] = (_Float16)tile[c][r];
    }
}

// ---------------------------------------------------------------------------
// Pack U: Upkr2[(d*128 + k2)*256 + j] = uint4 of 4 gate words;
// word g = { U_d[2*k2][g*256+j], U_d[2*k2+1][g*256+j] } as f16x2.
// ---------------------------------------------------------------------------
__global__ __launch_bounds__(256) void enc_pack_u16v2(
    const float* __restrict__ Uf, const float* __restrict__ Ub,
    uint4* __restrict__ Upkr2)
{
    int idx = blockIdx.x * 256 + threadIdx.x;     // 0 .. 65535
    if (idx >= 2 * 128 * 256) return;
    int d  = idx >> 15;
    int k2 = (idx >> 8) & 127;
    int j  = idx & 255;
    int k = 2 * k2;
    const float* Ud = d ? Ub : Uf;
    unsigned int w[4];
#pragma unroll
    for (int g = 0; g < 4; ++g) {
        f16x2 h;
        h.x = (_Float16)Ud[(size_t)k * NZ + g * 256 + j];
        h.y = (_Float16)Ud[(size_t)(k + 1) * NZ + g * 256 + j];
        w[g] = __builtin_bit_cast(unsigned int, h);
    }
    Upkr2[idx] = make_uint4(w[0], w[1], w[2], w[3]);
}

__global__ __launch_bounds__(256) void enc_zero(float* __restrict__ p, int n)
{
    int i = blockIdx.x * 256 + threadIdx.x;
    if (i < n) p[i] = 0.f;
}

// ---------------------------------------------------------------------------
// MFMA GEMM: xz16[r, n] = x16_row(r) . W_d[:, n] + b_d[n]   (unchanged)
// ---------------------------------------------------------------------------
__global__ __launch_bounds__(256) void enc_gemm16(
    const _Float16* __restrict__ x16, const _Float16* __restrict__ WT,
    const float* __restrict__ bf, const float* __restrict__ bb,
    _Float16* __restrict__ xz16, int c0, int CT)
{
    __shared__ __align__(16) _Float16 Ash[128][40];
    __shared__ __align__(16) _Float16 Bsh[128][40];

    const int t = threadIdx.x;
    const int r0 = blockIdx.x * 128;
    const int n0 = blockIdx.y * 128;
    const int MperD = BB * CT;
    const int d = r0 / MperD;

    const int srow = t >> 2;
    const int koff = (t & 3) * 8;

    auto xrowptr = [&](int r) -> const _Float16* {
        int rd = r - d * MperD;
        int b = rd / CT;
        int tl = rd - b * CT;
        int tsrc = d ? (TT - 1 - (c0 + tl)) : (c0 + tl);
        return x16 + ((size_t)b * TT + tsrc) * FF;
    };
    const _Float16* ap0 = xrowptr(r0 + srow);
    const _Float16* ap1 = xrowptr(r0 + 64 + srow);
    const _Float16* wp0 = WT + (size_t)(d * NZ + n0 + srow) * FF;
    const _Float16* wp1 = wp0 + (size_t)64 * FF;

    const int lane = t & 63;
    const int w = t >> 6;
    const int wm = w >> 1, wn = w & 1;
    const int l15 = lane & 15;
    const int kq = (lane >> 4) * 8;

    f32x4 acc[4][4];
#pragma unroll
    for (int i = 0; i < 4; ++i)
#pragma unroll
        for (int j = 0; j < 4; ++j) acc[i][j] = (f32x4)0.f;

    for (int ks = 0; ks < FF / 32; ++ks) {
        const int k0 = ks * 32;
        uint4 av0 = *(const uint4*)(ap0 + k0 + koff);
        uint4 av1 = *(const uint4*)(ap1 + k0 + koff);
        uint4 bv0 = *(const uint4*)(wp0 + k0 + koff);
        uint4 bv1 = *(const uint4*)(wp1 + k0 + koff);
        __syncthreads();
        *(uint4*)&Ash[srow][koff]      = av0;
        *(uint4*)&Ash[64 + srow][koff] = av1;
        *(uint4*)&Bsh[srow][koff]      = bv0;
        *(uint4*)&Bsh[64 + srow][koff] = bv1;
        __syncthreads();

        half8 af[4], bfr[4];
#pragma unroll
        for (int mf = 0; mf < 4; ++mf)
            af[mf] = *(const half8*)&Ash[wm * 64 + mf * 16 + l15][kq];
#pragma unroll
        for (int nf = 0; nf < 4; ++nf)
            bfr[nf] = *(const half8*)&Bsh[wn * 64 + nf * 16 + l15][kq];
#pragma unroll
        for (int mf = 0; mf < 4; ++mf)
#pragma unroll
            for (int nf = 0; nf < 4; ++nf)
                acc[mf][nf] = __builtin_amdgcn_mfma_f32_16x16x32_f16(
                    af[mf], bfr[nf], acc[mf][nf], 0, 0, 0);
    }

    const float* bd = d ? bb : bf;
    const int rbase = r0 + wm * 64;
    const int cbase = n0 + wn * 64;
#pragma unroll
    for (int nf = 0; nf < 4; ++nf) {
        const int cc = cbase + nf * 16 + l15;
        const float bia = bd[cc];
#pragma unroll
        for (int mf = 0; mf < 4; ++mf) {
#pragma unroll
            for (int rg = 0; rg < 4; ++rg) {
                int rr = rbase + mf * 16 + (lane >> 4) * 4 + rg;
                xz16[(size_t)rr * NZ + cc] = (_Float16)(acc[mf][nf][rg] + bia);
            }
        }
    }
}

// ---------------------------------------------------------------------------
// Pair-split single-CU recurrence: 128 blocks = chains, 512 threads.
// __launch_bounds__(512, 1): VGPR ceiling 512 -> the allocator can honor the
// 192 asm-pinned registers (R10-R12 lesson: 1024-thread blocks are hard-capped
// at 64 VGPRs and everything spills to scratch/L2).
// t = j*2 + s: lane s owns k-half s (64 k2-pairs) x 4 gates of unit j.
// U per thread = 64 uint4: 48 ASM-PINNED in VGPRs + 16 in LDS [16][512].
// ALL of U on-CU; no L2 tier; FETCH = xz stream only.
// h[256] f16 flat in LDS; even lanes read half0, odd half1 (2 addrs/wave,
// 2-way broadcast = free). Pair reduce = ONE dpp-add; gates duplicated x2.
// 2 raw lgkm barriers/step; no cross-CU exchange, no spin.
// ---------------------------------------------------------------------------
__device__ __forceinline__ float sigm_f(float xv)
{
    return 1.0f / (1.0f + __expf(-xv));
}
__device__ __forceinline__ float tanh_f(float xv)
{
    return 2.0f / (1.0f + __expf(-2.0f * xv)) - 1.0f;
}

__global__ __launch_bounds__(512, 1) void enc_lstm_pair(
    const _Float16* __restrict__ xz16, const uint4* __restrict__ Upkr2,
    float* __restrict__ hstate, float* __restrict__ cstate,
    float* __restrict__ out, int c0, int CT)
{
    extern __shared__ char smem2[];
    u32x4* ulds = (u32x4*)smem2;                     // [16][512] u32x4
    char*  hbase = smem2 + ULDS_BYTES;               // 512 B h

    const int t = threadIdx.x;
    const int s = t & 1;           // k-half
    const int j = t >> 1;          // unit 0..255
    const int c = blockIdx.x;      // chain 0..127
    const int d = c >> 6;
    const int b = c & 63;

    // ---- persistent U: 64 words; 48 asm-pinned + 16 LDS ----
    const u32x4* Uq = (const u32x4*)(Upkr2 + ((size_t)d * 128 + s * 64) * 256 + j);

    u32x4 ureg[UREG];
#pragma unroll
    for (int m = 0; m < UREG; ++m) {
        const u32x4* p = Uq + (size_t)m * 256;
        asm volatile("global_load_dwordx4 %0, %1, off"
                     : "=v"(ureg[m]) : "v"(p) : "memory");
    }
#pragma unroll
    for (int m = 0; m < ULDS; ++m)
        ulds[(size_t)m * 512 + t] = Uq[(size_t)(UREG + m) * 256];

    asm volatile("s_waitcnt vmcnt(0)" ::: "memory");
    __builtin_amdgcn_sched_barrier(0);               // rule #18 fence

    // ---- state init ----
    float cr = cstate[(size_t)c * UU + j];           // duplicated across pair
    float hn = 0.f;
    if (t < 256) {
        _Float16 hv = (_Float16)hstate[(size_t)c * UU + t];
        *(unsigned short*)(hbase + t * 2) = __builtin_bit_cast(unsigned short, hv);
    }
    __syncthreads();

    const _Float16* xzrow = xz16 + (size_t)c * CT * NZ;
    float* outb = out + (size_t)b * TT * (2 * UU) + d * UU;
    const char* hrd = hbase + s * 256;               // this lane's h half

    // first step's xz: lane s handles gates 2s, 2s+1 of unit j
    unsigned short xa = *((const unsigned short*)xzrow + (2 * s) * 256 + j);
    unsigned short xb = *((const unsigned short*)xzrow + (2 * s + 1) * 256 + j);

    for (int tl = 0; tl < CT; ++tl) {
        float a0 = 0.f, a1 = 0.f, a2 = 0.f, a3 = 0.f;
        auto dotw = [&](const u32x4& uv, unsigned int hw) {
            f16x2 h2 = bc16(hw);
            a0 = __builtin_amdgcn_fdot2(h2, bc16(uv.x), a0, false);
            a1 = __builtin_amdgcn_fdot2(h2, bc16(uv.y), a1, false);
            a2 = __builtin_amdgcn_fdot2(h2, bc16(uv.z), a2, false);
            a3 = __builtin_amdgcn_fdot2(h2, bc16(uv.w), a3, false);
        };

        // r = 0..11: register tier (words 0..47)
#pragma unroll
        for (int r = 0; r < 12; ++r) {
            u32x4 hq = *(const u32x4*)(hrd + r * 16);
            dotw(ureg[4 * r + 0], hq.x);
            dotw(ureg[4 * r + 1], hq.y);
            dotw(ureg[4 * r + 2], hq.z);
            dotw(ureg[4 * r + 3], hq.w);
        }
        // r = 12..15: LDS tier (words 48..63 = rows 0..15), explicit elements
#pragma unroll
        for (int r = 12; r < 16; ++r) {
            u32x4 hq = *(const u32x4*)(hrd + r * 16);
            u32x4 uv0 = ulds[(size_t)(4 * (r - 12) + 0) * 512 + t];
            u32x4 uv1 = ulds[(size_t)(4 * (r - 12) + 1) * 512 + t];
            u32x4 uv2 = ulds[(size_t)(4 * (r - 12) + 2) * 512 + t];
            u32x4 uv3 = ulds[(size_t)(4 * (r - 12) + 3) * 512 + t];
            dotw(uv0, hq.x);
            dotw(uv1, hq.y);
            dotw(uv2, hq.z);
            dotw(uv3, hq.w);
        }

        // inject xz: lane s adds gates 2s,2s+1 (counted once after pair-sum)
        {
            float xva = (float)__builtin_bit_cast(_Float16, xa);
            float xvb = (float)__builtin_bit_cast(_Float16, xb);
            a0 += (s == 0) ? xva : 0.f;
            a1 += (s == 0) ? xvb : 0.f;
            a2 += (s == 1) ? xva : 0.f;
            a3 += (s == 1) ? xvb : 0.f;
        }
        // pair reduce: both lanes get full z
        float zi = psum(a0), zf = psum(a1), zg = psum(a2), zo = psum(a3);

        // gates (duplicated across pair — deterministic identical results)
        float ig = sigm_f(zi), fg = sigm_f(zf), gg = tanh_f(zg), og = sigm_f(zo);
        cr = fg * cr + ig * gg;
        hn = og * tanh_f(cr);
        unsigned short hbits =
            __builtin_bit_cast(unsigned short, (_Float16)hn);

        // prefetch next step's xz (vmcnt survives raw barriers)
        {
            int tn = (tl + 1 < CT) ? tl + 1 : tl;
            const unsigned short* pn =
                (const unsigned short*)(xzrow + (size_t)tn * NZ) + j;
            xa = pn[(2 * s) * 256];
            xb = pn[(2 * s + 1) * 256];
        }

        bar_lgkm();                          // bar1: all h reads complete
        if (s == 0) {
            *(unsigned short*)(hbase + j * 2) = hbits;
            int tsrc = d ? (TT - 1 - (c0 + tl)) : (c0 + tl);
            outb[(size_t)tsrc * (2 * UU) + j] = hn;
        }
        bar_lgkm();                          // bar2: new h visible
    }

    if (s == 0) {
        hstate[(size_t)c * UU + j] = hn;
        cstate[(size_t)c * UU + j] = cr;
    }
}

// ---------------------------------------------------------------------------
// Final h/c copy into d_out tail sections
// ---------------------------------------------------------------------------
__global__ __launch_bounds__(256) void enc_final(
    const float* __restrict__ hstate, const float* __restrict__ cstate,
    float* __restrict__ out)
{
    int idx = blockIdx.x * 256 + threadIdx.x;
    if (idx >= 2 * BB * UU) return;
    int d = idx / (BB * UU);
    int rem = idx - d * (BB * UU);
    int b = rem / UU;
    int j = rem - b * UU;
    size_t OUT_H = (size_t)BB * TT * (2 * UU);
    size_t HSZ = (size_t)BB * (2 * UU);
    out[OUT_H + (size_t)b * (2 * UU) + d * UU + j] = hstate[idx];
    out[OUT_H + HSZ + (size_t)b * (2 * UU) + d * UU + j] = cstate[idx];
}

// ---------------------------------------------------------------------------
extern "C" void kernel_launch(void* const* d_in, const int* in_sizes, int n_in,
                              void* d_out, int out_size, void* d_ws, size_t ws_size,
                              hipStream_t stream)
{
    const float* x  = (const float*)d_in[0];
    const float* Wf = (const float*)d_in[1];
    const float* Uf = (const float*)d_in[2];
    const float* bf = (const float*)d_in[3];
    const float* Wb = (const float*)d_in[4];
    const float* Ub = (const float*)d_in[5];
    const float* bb = (const float*)d_in[6];
    float* out = (float*)d_out;

    const size_t x16_bytes   = (size_t)BB * TT * FF * 2;             // 64 MiB
    const size_t wt_bytes    = (size_t)2 * NZ * FF * 2;              // 2 MiB
    const size_t upk_bytes   = (size_t)2 * 128 * 256 * sizeof(uint4);// 1 MiB
    const size_t state_bytes = (size_t)2 * BB * UU * sizeof(float);  // 128 KiB each
    const size_t fixed = x16_bytes + wt_bytes + upk_bytes + 2 * state_bytes;

    int CT = TT;
    while (CT > 8) {
        size_t need = fixed + (size_t)2 * BB * CT * NZ * 2;
        if (need <= ws_size) break;
        CT >>= 1;
    }

    char* wsb = (char*)d_ws;
    _Float16* x16 = (_Float16*)wsb;
    _Float16* WT  = (_Float16*)(wsb + x16_bytes);
    uint4* Upkr2  = (uint4*)(wsb + x16_bytes + wt_bytes);
    float* hstate = (float*)(wsb + x16_bytes + wt_bytes + upk_bytes);
    float* cstate = hstate + 2 * BB * UU;
    _Float16* xz16 = (_Float16*)(wsb + fixed);

    (void)hipFuncSetAttribute(reinterpret_cast<const void*>(enc_lstm_pair),
                              hipFuncAttributeMaxDynamicSharedMemorySize,
                              (int)LSTM_SHBYTES);

    enc_cast_x<<<4096, 256, 0, stream>>>(x, x16, BB * TT * FF / 4);
    enc_cast_wt<<<dim3(8, 16, 2), 256, 0, stream>>>(Wf, Wb, WT);
    enc_pack_u16v2<<<(2 * 128 * 256 + 255) / 256, 256, 0, stream>>>(Uf, Ub, Upkr2);
    enc_zero<<<(2 * 2 * BB * UU + 255) / 256, 256, 0, stream>>>(hstate, 2 * 2 * BB * UU);

    for (int c0 = 0; c0 < TT; c0 += CT) {
        dim3 ggrid((2 * BB * CT) / 128, NZ / 128);
        enc_gemm16<<<ggrid, 256, 0, stream>>>(x16, WT, bf, bb, xz16, c0, CT);
        enc_lstm_pair<<<128, 512, LSTM_SHBYTES, stream>>>(
            xz16, Upkr2, hstate, cstate, out, c0, CT);
    }
    enc_final<<<(2 * BB * UU + 255) / 256, 256, 0, stream>>>(hstate, cstate, out);
}

// Round 15
// 1739.637 us; speedup vs baseline: 1.7475x; 1.1155x over previous
//
#include <hip/hip_runtime.h>
#include <cstdint>
#include <cstddef>

typedef _Float16 f16x2 __attribute__((ext_vector_type(2)));
typedef _Float16 half4 __attribute__((ext_vector_type(4)));
typedef _Float16 half8 __attribute__((ext_vector_type(8)));
typedef float f32x4 __attribute__((ext_vector_type(4)));
typedef unsigned int u32x4 __attribute__((ext_vector_type(4)));

static constexpr int BB = 64;    // batch
static constexpr int TT = 1024;  // time steps
static constexpr int FF = 512;   // input features
static constexpr int UU = 256;   // hidden units per direction
static constexpr int NZ = 1024;  // 4*UU gate width

// U-half per block (256 KiB f16) = per-thread 32 uint4:
//   14 asm-pinned VGPR words (56 regs, safely under the 128-reg allocator cap
//   observed in R10-R14) + 18 LDS rows [18][512] (144 KiB).
static constexpr int UREG = 14;
static constexpr int ULDS = 18;
static constexpr size_t ULDS_BYTES = (size_t)ULDS * 512 * 16;    // 147456 B
static constexpr size_t PARTS_BYTES = 3 * 128 * 16;              // 6144 B
static constexpr size_t HSH_BYTES = 512;
static constexpr size_t LSTM_SHBYTES = ULDS_BYTES + PARTS_BYTES + HSH_BYTES; // 154112

__device__ __forceinline__ f16x2 bc16(unsigned int v) { return __builtin_bit_cast(f16x2, v); }

__device__ __forceinline__ void st_u32_rlx(unsigned int* p, unsigned int v)
{
    __hip_atomic_store(p, v, __ATOMIC_RELAXED, __HIP_MEMORY_SCOPE_AGENT);
}
__device__ __forceinline__ unsigned int ld_u32_rlx(const unsigned int* p)
{
    return __hip_atomic_load(p, __ATOMIC_RELAXED, __HIP_MEMORY_SCOPE_AGENT);
}

// Raw barrier: drains LDS ops only; vmcnt (global loads) survives.
__device__ __forceinline__ void bar_lgkm()
{
    asm volatile("s_waitcnt lgkmcnt(0)\n\ts_barrier" ::: "memory");
}

// ---------------------------------------------------------------------------
// Cast x fp32 -> f16 (flat)
// ---------------------------------------------------------------------------
__global__ __launch_bounds__(256) void enc_cast_x(
    const float* __restrict__ x, _Float16* __restrict__ x16, int n4)
{
    int stride = gridDim.x * 256;
    for (int i = blockIdx.x * 256 + threadIdx.x; i < n4; i += stride) {
        float4 v = ((const float4*)x)[i];
        half4 o;
        o.x = (_Float16)v.x; o.y = (_Float16)v.y;
        o.z = (_Float16)v.z; o.w = (_Float16)v.w;
        ((half4*)x16)[i] = o;
    }
}

// ---------------------------------------------------------------------------
// W [512,1024] fp32 -> WT [dir][1024][512] f16 (transposed)
// ---------------------------------------------------------------------------
__global__ __launch_bounds__(256) void enc_cast_wt(
    const float* __restrict__ Wf, const float* __restrict__ Wb,
    _Float16* __restrict__ WT)
{
    __shared__ float tile[64][65];
    const int t = threadIdx.x;
    const int k0 = blockIdx.x * 64;
    const int n0 = blockIdx.y * 64;
    const int d = blockIdx.z;
    const float* W = d ? Wb : Wf;
    _Float16* WTd = WT + (size_t)d * NZ * FF;
#pragma unroll
    for (int p = 0; p < 16; ++p) {
        int idx = p * 256 + t;
        int r = idx >> 6, c = idx & 63;
        tile[r][c] = W[(size_t)(k0 + r) * NZ + n0 + c];
    }
    __syncthreads();
#pragma unroll
    for (int p = 0; p < 16; ++p) {
        int idx = p * 256 + t;
        int r = idx >> 6, c = idx & 63;
        WTd[(size_t)(n0 + r) * FF + k0 + c] = (_Float16)tile[c][r];
    }
}

// ---------------------------------------------------------------------------
// Pack U: Upkr2[(d*128 + k2)*256 + j] = uint4 of 4 gate words;
// word g = { U_d[2*k2][g*256+j], U_d[2*k2+1][g*256+j] } as f16x2.
// ---------------------------------------------------------------------------
__global__ __launch_bounds__(256) void enc_pack_u16v2(
    const float* __restrict__ Uf, const float* __restrict__ Ub,
    uint4* __restrict__ Upkr2)
{
    int idx = blockIdx.x * 256 + threadIdx.x;     // 0 .. 65535
    if (idx >= 2 * 128 * 256) return;
    int d  = idx >> 15;
    int k2 = (idx >> 8) & 127;
    int j  = idx & 255;
    int k = 2 * k2;
    const float* Ud = d ? Ub : Uf;
    unsigned int w[4];
#pragma unroll
    for (int g = 0; g < 4; ++g) {
        f16x2 h;
        h.x = (_Float16)Ud[(size_t)k * NZ + g * 256 + j];
        h.y = (_Float16)Ud[(size_t)(k + 1) * NZ + g * 256 + j];
        w[g] = __builtin_bit_cast(unsigned int, h);
    }
    Upkr2[idx] = make_uint4(w[0], w[1], w[2], w[3]);
}

__global__ __launch_bounds__(256) void enc_zero(float* __restrict__ p, int n)
{
    int i = blockIdx.x * 256 + threadIdx.x;
    if (i < n) p[i] = 0.f;
}

// ---------------------------------------------------------------------------
// MFMA GEMM: xz16[r, n] = x16_row(r) . W_d[:, n] + b_d[n]   (unchanged)
// ---------------------------------------------------------------------------
__global__ __launch_bounds__(256) void enc_gemm16(
    const _Float16* __restrict__ x16, const _Float16* __restrict__ WT,
    const float* __restrict__ bf, const float* __restrict__ bb,
    _Float16* __restrict__ xz16, int c0, int CT)
{
    __shared__ __align__(16) _Float16 Ash[128][40];
    __shared__ __align__(16) _Float16 Bsh[128][40];

    const int t = threadIdx.x;
    const int r0 = blockIdx.x * 128;
    const int n0 = blockIdx.y * 128;
    const int MperD = BB * CT;
    const int d = r0 / MperD;

    const int srow = t >> 2;
    const int koff = (t & 3) * 8;

    auto xrowptr = [&](int r) -> const _Float16* {
        int rd = r - d * MperD;
        int b = rd / CT;
        int tl = rd - b * CT;
        int tsrc = d ? (TT - 1 - (c0 + tl)) : (c0 + tl);
        return x16 + ((size_t)b * TT + tsrc) * FF;
    };
    const _Float16* ap0 = xrowptr(r0 + srow);
    const _Float16* ap1 = xrowptr(r0 + 64 + srow);
    const _Float16* wp0 = WT + (size_t)(d * NZ + n0 + srow) * FF;
    const _Float16* wp1 = wp0 + (size_t)64 * FF;

    const int lane = t & 63;
    const int w = t >> 6;
    const int wm = w >> 1, wn = w & 1;
    const int l15 = lane & 15;
    const int kq = (lane >> 4) * 8;

    f32x4 acc[4][4];
#pragma unroll
    for (int i = 0; i < 4; ++i)
#pragma unroll
        for (int j = 0; j < 4; ++j) acc[i][j] = (f32x4)0.f;

    for (int ks = 0; ks < FF / 32; ++ks) {
        const int k0 = ks * 32;
        uint4 av0 = *(const uint4*)(ap0 + k0 + koff);
        uint4 av1 = *(const uint4*)(ap1 + k0 + koff);
        uint4 bv0 = *(const uint4*)(wp0 + k0 + koff);
        uint4 bv1 = *(const uint4*)(wp1 + k0 + koff);
        __syncthreads();
        *(uint4*)&Ash[srow][koff]      = av0;
        *(uint4*)&Ash[64 + srow][koff] = av1;
        *(uint4*)&Bsh[srow][koff]      = bv0;
        *(uint4*)&Bsh[64 + srow][koff] = bv1;
        __syncthreads();

        half8 af[4], bfr[4];
#pragma unroll
        for (int mf = 0; mf < 4; ++mf)
            af[mf] = *(const half8*)&Ash[wm * 64 + mf * 16 + l15][kq];
#pragma unroll
        for (int nf = 0; nf < 4; ++nf)
            bfr[nf] = *(const half8*)&Bsh[wn * 64 + nf * 16 + l15][kq];
#pragma unroll
        for (int mf = 0; mf < 4; ++mf)
#pragma unroll
            for (int nf = 0; nf < 4; ++nf)
                acc[mf][nf] = __builtin_amdgcn_mfma_f32_16x16x32_f16(
                    af[mf], bfr[nf], acc[mf][nf], 0, 0, 0);
    }

    const float* bd = d ? bb : bf;
    const int rbase = r0 + wm * 64;
    const int cbase = n0 + wn * 64;
#pragma unroll
    for (int nf = 0; nf < 4; ++nf) {
        const int cc = cbase + nf * 16 + l15;
        const float bia = bd[cc];
#pragma unroll
        for (int mf = 0; mf < 4; ++mf) {
#pragma unroll
            for (int rg = 0; rg < 4; ++rg) {
                int rr = rbase + mf * 16 + (lane >> 4) * 4 + rg;
                xz16[(size_t)rr * NZ + cc] = (_Float16)(acc[mf][nf][rg] + bia);
            }
        }
    }
}

// ---------------------------------------------------------------------------
// Split-chain recurrence v5 = R8's proven structure + explicit U storage.
// 256 blocks: jh = beta>>7, chain = beta&127, partner = beta^128.
// Thread (s = t>>7 k-quarter, jl = t&127). Per-thread U slice = 32 uint4
// (k2 m=0..31, 4 gate-words each): m<14 ASM-PINNED VGPR (56 regs; under the
// 128 cap the allocator actually grants), m=14..31 in LDS [18][512].
// ZERO per-step global U traffic (R5-R8 silently streamed ~17 words/thread
// from L2 every step: VGPR=88 < 128 needed, FETCH 210MB vs 135 baseline).
// Phases per step (tl consumes h_{c0+tl}, produces h_{c0+tl+1}):
//   ph1: own-half dots  || isx waits for partner tag c0+tl (tl>0)
//   ph2: partner-half dots
//   ph3: s==0 reduce+gates+publish+out; isx samples next word
// Exchange protocol (parity slot + step-tagged words) byte-identical to R8.
// ---------------------------------------------------------------------------
__device__ __forceinline__ float sigm_f(float xv)
{
    return 1.0f / (1.0f + __expf(-xv));
}
__device__ __forceinline__ float tanh_f(float xv)
{
    return 2.0f / (1.0f + __expf(-2.0f * xv)) - 1.0f;
}

__global__ __launch_bounds__(512, 1) void enc_lstm_split(
    const _Float16* __restrict__ xz16, const uint4* __restrict__ Upkr2,
    float* __restrict__ hstate, float* __restrict__ cstate,
    unsigned int* __restrict__ hbuf,
    float* __restrict__ out, int c0, int CT)
{
    extern __shared__ char smem2[];
    u32x4*     ulds  = (u32x4*)smem2;                            // [18][512]
    float4*    parts = (float4*)(smem2 + ULDS_BYTES);            // 3*128
    _Float16*  hsh   = (_Float16*)(smem2 + ULDS_BYTES + PARTS_BYTES);
    u32x4*     hshq  = (u32x4*)hsh;

    const int t  = threadIdx.x;
    const int s  = t >> 7;          // k-quarter 0..3
    const int jl = t & 127;
    const int beta = blockIdx.x;
    const int jh = beta >> 7;                          // j-half
    const int c  = beta & 127;                         // chain 0..127
    const int d  = c >> 6;
    const int b  = c & 63;
    const int j  = jh * 128 + jl;
    const int partner = beta ^ 128;
    const bool own = ((s >> 1) == jh);    // k-range uses own h-half
    const bool isx = (s == (jh ? 1 : 2)); // exchange group (partner-consuming, non-publisher)

    // ---- persistent U: 14 asm-pinned + 18 LDS rows ----
    const u32x4* Uq = (const u32x4*)(Upkr2 + ((size_t)d * 128 + s * 32) * 256 + j);
    u32x4 ureg[UREG];
#pragma unroll
    for (int m = 0; m < UREG; ++m) {
        const u32x4* p = Uq + (size_t)m * 256;
        asm volatile("global_load_dwordx4 %0, %1, off"
                     : "=v"(ureg[m]) : "v"(p) : "memory");
    }
#pragma unroll
    for (int m = 0; m < ULDS; ++m)
        ulds[(size_t)m * 512 + t] = Uq[(size_t)(UREG + m) * 256];

    asm volatile("s_waitcnt vmcnt(0)" ::: "memory");
    __builtin_amdgcn_sched_barrier(0);               // rule #18 fence

    // ---- state init ----
    float cr = 0.f, hn = 0.f;
    if (s == 0) cr = cstate[(size_t)c * UU + j];
    if (t < 256) hsh[t] = (_Float16)hstate[(size_t)c * UU + t];
    __syncthreads();

    const _Float16* xzrow = xz16 + (size_t)c * CT * NZ;
    float* outb = out + (size_t)b * TT * (2 * UU) + d * UU;

    // ---- pre-loop prefetches ----
    unsigned short xp0 = 0, xp1 = 0, xp2 = 0, xp3 = 0;
    if (s == 0) {
        const unsigned short* p = (const unsigned short*)xzrow + j;
        xp0 = p[0]; xp1 = p[256]; xp2 = p[512]; xp3 = p[768];
    }
    unsigned int pref = 0;   // tag 0 never matches a real htag

    // full 32-k2 dot: 14 register words + 18 LDS words, all indices static
    auto dot32 = [&](float& a0, float& a1, float& a2, float& a3) {
        auto dotw = [&](const u32x4& uv, unsigned int hw) {
            f16x2 h2 = bc16(hw);
            a0 = __builtin_amdgcn_fdot2(h2, bc16(uv.x), a0, false);
            a1 = __builtin_amdgcn_fdot2(h2, bc16(uv.y), a1, false);
            a2 = __builtin_amdgcn_fdot2(h2, bc16(uv.z), a2, false);
            a3 = __builtin_amdgcn_fdot2(h2, bc16(uv.w), a3, false);
        };
        auto L = [&](int w) -> u32x4 { return ulds[(size_t)w * 512 + t]; };
        {   // r=0..2: reg words 0..11
            u32x4 hq = hshq[s * 8 + 0];
            dotw(ureg[0], hq.x); dotw(ureg[1], hq.y);
            dotw(ureg[2], hq.z); dotw(ureg[3], hq.w);
        }
        {
            u32x4 hq = hshq[s * 8 + 1];
            dotw(ureg[4], hq.x); dotw(ureg[5], hq.y);
            dotw(ureg[6], hq.z); dotw(ureg[7], hq.w);
        }
        {
            u32x4 hq = hshq[s * 8 + 2];
            dotw(ureg[8], hq.x); dotw(ureg[9], hq.y);
            dotw(ureg[10], hq.z); dotw(ureg[11], hq.w);
        }
        {   // r=3: words 12,13 reg; 14,15 -> LDS rows 0,1
            u32x4 hq = hshq[s * 8 + 3];
            dotw(ureg[12], hq.x); dotw(ureg[13], hq.y);
            dotw(L(0), hq.z); dotw(L(1), hq.w);
        }
        {   // r=4: LDS rows 2..5
            u32x4 hq = hshq[s * 8 + 4];
            dotw(L(2), hq.x); dotw(L(3), hq.y);
            dotw(L(4), hq.z); dotw(L(5), hq.w);
        }
        {   // r=5: LDS rows 6..9
            u32x4 hq = hshq[s * 8 + 5];
            dotw(L(6), hq.x); dotw(L(7), hq.y);
            dotw(L(8), hq.z); dotw(L(9), hq.w);
        }
        {   // r=6: LDS rows 10..13
            u32x4 hq = hshq[s * 8 + 6];
            dotw(L(10), hq.x); dotw(L(11), hq.y);
            dotw(L(12), hq.z); dotw(L(13), hq.w);
        }
        {   // r=7: LDS rows 14..17
            u32x4 hq = hshq[s * 8 + 7];
            dotw(L(14), hq.x); dotw(L(15), hq.y);
            dotw(L(16), hq.z); dotw(L(17), hq.w);
        }
    };

    for (int tl = 0; tl < CT; ++tl) {
        const int step = c0 + tl + 1;   // h produced this iteration
        const int htag = c0 + tl;       // partner h consumed this iteration

        // ---- phase 1: own-half dots || exchange finalize ----
        float a0 = 0.f, a1 = 0.f, a2 = 0.f, a3 = 0.f;
        if (own) {
            dot32(a0, a1, a2, a3);
            if (s) parts[(s - 1) * 128 + jl] = make_float4(a0, a1, a2, a3);
        }
        if (isx && tl > 0) {
            const unsigned int* pp =
                &hbuf[((size_t)(htag & 1) * 256 + partner) * 128 + jl];
            unsigned int v = pref;
            while ((v >> 16) != (unsigned int)htag)
                v = ld_u32_rlx(pp);
            hsh[(1 - jh) * 128 + jl] =
                __builtin_bit_cast(_Float16, (unsigned short)(v & 0xffffu));
        }
        bar_lgkm();                                // bar1: partner h in hsh

        // ---- phase 2: partner-half dots ----
        if (!own) {
            dot32(a0, a1, a2, a3);
            if (s) parts[(s - 1) * 128 + jl] = make_float4(a0, a1, a2, a3);
        }
        bar_lgkm();                                // bar2: all partials ready

        // ---- phase 3: gates + publish (s==0) ; prefetch sample (isx) ----
        if (s == 0) {
            float4 p1 = parts[jl], p2 = parts[128 + jl], p3 = parts[256 + jl];
            float zi = a0 + p1.x + p2.x + p3.x
                     + (float)__builtin_bit_cast(_Float16, xp0);
            float zf = a1 + p1.y + p2.y + p3.y
                     + (float)__builtin_bit_cast(_Float16, xp1);
            float zg = a2 + p1.z + p2.z + p3.z
                     + (float)__builtin_bit_cast(_Float16, xp2);
            float zo = a3 + p1.w + p2.w + p3.w
                     + (float)__builtin_bit_cast(_Float16, xp3);
            float ig = sigm_f(zi), fg = sigm_f(zf), gg = tanh_f(zg), og = sigm_f(zo);
            cr = fg * cr + ig * gg;
            hn = og * tanh_f(cr);
            _Float16 h16 = (_Float16)hn;
            st_u32_rlx(&hbuf[((size_t)(step & 1) * 256 + beta) * 128 + jl],
                       ((unsigned int)step << 16)
                       | (unsigned int)__builtin_bit_cast(unsigned short, h16));
            hsh[j] = h16;
            int tsrc = d ? (TT - 1 - (c0 + tl)) : (c0 + tl);
            outb[(size_t)tsrc * (2 * UU) + j] = hn;
            int tn = (tl + 1 < CT) ? tl + 1 : tl;
            const unsigned short* pn =
                (const unsigned short*)(xzrow + (size_t)tn * NZ) + j;
            xp0 = pn[0]; xp1 = pn[256]; xp2 = pn[512]; xp3 = pn[768];
        }
        if (isx) {
            pref = ld_u32_rlx(&hbuf[((size_t)(step & 1) * 256 + partner) * 128 + jl]);
        }
        bar_lgkm();                                // bar3: own hsh half updated
    }

    if (s == 0) {
        hstate[(size_t)c * UU + j] = hn;
        cstate[(size_t)c * UU + j] = cr;
    }
}

// ---------------------------------------------------------------------------
// Final h/c copy into d_out tail sections
// ---------------------------------------------------------------------------
__global__ __launch_bounds__(256) void enc_final(
    const float* __restrict__ hstate, const float* __restrict__ cstate,
    float* __restrict__ out)
{
    int idx = blockIdx.x * 256 + threadIdx.x;
    if (idx >= 2 * BB * UU) return;
    int d = idx / (BB * UU);
    int rem = idx - d * (BB * UU);
    int b = rem / UU;
    int j = rem - b * UU;
    size_t OUT_H = (size_t)BB * TT * (2 * UU);
    size_t HSZ = (size_t)BB * (2 * UU);
    out[OUT_H + (size_t)b * (2 * UU) + d * UU + j] = hstate[idx];
    out[OUT_H + HSZ + (size_t)b * (2 * UU) + d * UU + j] = cstate[idx];
}

// ---------------------------------------------------------------------------
extern "C" void kernel_launch(void* const* d_in, const int* in_sizes, int n_in,
                              void* d_out, int out_size, void* d_ws, size_t ws_size,
                              hipStream_t stream)
{
    const float* x  = (const float*)d_in[0];
    const float* Wf = (const float*)d_in[1];
    const float* Uf = (const float*)d_in[2];
    const float* bf = (const float*)d_in[3];
    const float* Wb = (const float*)d_in[4];
    const float* Ub = (const float*)d_in[5];
    const float* bb = (const float*)d_in[6];
    float* out = (float*)d_out;

    const size_t x16_bytes   = (size_t)BB * TT * FF * 2;             // 64 MiB
    const size_t wt_bytes    = (size_t)2 * NZ * FF * 2;              // 2 MiB
    const size_t upk_bytes   = (size_t)2 * 128 * 256 * sizeof(uint4);// 1 MiB
    const size_t state_bytes = (size_t)2 * BB * UU * sizeof(float);  // 128 KiB each
    const size_t hbuf_bytes  = (size_t)2 * 256 * 128 * 4;            // 256 KiB
    const size_t fixed = x16_bytes + wt_bytes + upk_bytes + 2 * state_bytes
                       + hbuf_bytes;

    int CT = TT;
    while (CT > 8) {
        size_t need = fixed + (size_t)2 * BB * CT * NZ * 2;
        if (need <= ws_size) break;
        CT >>= 1;
    }

    char* wsb = (char*)d_ws;
    _Float16* x16 = (_Float16*)wsb;
    _Float16* WT  = (_Float16*)(wsb + x16_bytes);
    uint4* Upkr2  = (uint4*)(wsb + x16_bytes + wt_bytes);
    float* hstate = (float*)(wsb + x16_bytes + wt_bytes + upk_bytes);
    float* cstate = hstate + 2 * BB * UU;
    unsigned int* hbuf = (unsigned int*)(wsb + x16_bytes + wt_bytes + upk_bytes
                                         + 2 * state_bytes);
    _Float16* xz16 = (_Float16*)(wsb + fixed);

    (void)hipFuncSetAttribute(reinterpret_cast<const void*>(enc_lstm_split),
                              hipFuncAttributeMaxDynamicSharedMemorySize,
                              (int)LSTM_SHBYTES);

    enc_cast_x<<<4096, 256, 0, stream>>>(x, x16, BB * TT * FF / 4);
    enc_cast_wt<<<dim3(8, 16, 2), 256, 0, stream>>>(Wf, Wb, WT);
    enc_pack_u16v2<<<(2 * 128 * 256 + 255) / 256, 256, 0, stream>>>(Uf, Ub, Upkr2);
    enc_zero<<<(2 * 2 * BB * UU + 255) / 256, 256, 0, stream>>>(hstate, 2 * 2 * BB * UU);

    for (int c0 = 0; c0 < TT; c0 += CT) {
        dim3 ggrid((2 * BB * CT) / 128, NZ / 128);
        enc_gemm16<<<ggrid, 256, 0, stream>>>(x16, WT, bf, bb, xz16, c0, CT);
        enc_lstm_split<<<256, 512, LSTM_SHBYTES, stream>>>(
            xz16, Upkr2, hstate, cstate, hbuf, out, c0, CT);
    }
    enc_final<<<(2 * BB * UU + 255) / 256, 256, 0, stream>>>(hstate, cstate, out);
}